// Round 5
// baseline (2724.009 us; speedup 1.0000x reference)
//
#include <hip/hip_runtime.h>

typedef __attribute__((ext_vector_type(8))) short bf16x8;
typedef __attribute__((ext_vector_type(4))) float f32x4;

__device__ __forceinline__ short f2bf(float f) {
  union { float f; unsigned u; } v; v.f = f;
  unsigned r = (v.u + 0x7fffu + ((v.u >> 16) & 1u)) >> 16;
  return (short)r;
}
__device__ __forceinline__ float bf2f(short s) {
  union { unsigned u; float f; } v; v.u = ((unsigned)(unsigned short)s) << 16;
  return v.f;
}
__device__ __forceinline__ float sigmf(float x) { return 1.f / (1.f + __expf(-x)); }

__device__ __forceinline__ void stage_row_f32(const float* __restrict__ src, short* dst,
                                              int kb, int k0, int K) {
  if (kb + k0 + 15 < K) {
    const f32x4* p4 = (const f32x4*)src;
#pragma unroll
    for (int g = 0; g < 4; g++) {
      f32x4 v = p4[g];
      dst[g * 4 + 0] = f2bf(v.x); dst[g * 4 + 1] = f2bf(v.y);
      dst[g * 4 + 2] = f2bf(v.z); dst[g * 4 + 3] = f2bf(v.w);
    }
  } else {
#pragma unroll
    for (int j = 0; j < 16; j++) {
      float v = (kb + k0 + j < K) ? src[j] : 0.f;
      dst[j] = f2bf(v);
    }
  }
}

// Input projection: C = relu(A @ W^T + bias), A fp32 [B,T,K] (logical row r=t*32+b at
// physical row b*256+t), C bf16 in chunk-16 layout:
//   elem(r=t*32+b, col) at ((t*64 + (col>>4))*512 + b*16 + (col&15)).
__global__ __launch_bounds__(256) void proj_gemm(
    const float* __restrict__ A, int lda,
    const float* __restrict__ W, int ldw,
    const float* __restrict__ bias,
    short* __restrict__ C, int coloff, int K) {
  __shared__ short As[128][40];
  __shared__ short Bs[128][40];
  const int tid = threadIdx.x;
  const int m0 = blockIdx.x << 7, n0 = blockIdx.y << 7;
  const int w = tid >> 6, lane = tid & 63, m16 = lane & 15, q = lane >> 4;
  const f32x4 vzero = {0.f, 0.f, 0.f, 0.f};
  f32x4 acc[2][8];
#pragma unroll
  for (int mt = 0; mt < 2; mt++)
#pragma unroll
    for (int nt = 0; nt < 8; nt++) acc[mt][nt] = vzero;

  const int nk = (K + 31) >> 5;
  const int r = tid >> 1, k0 = (tid & 1) << 4;
  for (int kc = 0; kc < nk; kc++) {
    const int kb = kc << 5;
    {
      const int gr = m0 + r;
      const size_t arow = (size_t)(gr & 31) * 256 + (size_t)(gr >> 5);
      stage_row_f32(A + arow * (size_t)lda + kb + k0, &As[r][k0], kb, k0, K);
    }
    {
      const float* bp = W + (size_t)(n0 + r) * ldw + kb + k0;
      stage_row_f32(bp, &Bs[r][k0], kb, k0, K);
    }
    __syncthreads();
    bf16x8 af[2], bfv[8];
#pragma unroll
    for (int mt = 0; mt < 2; mt++)
      af[mt] = *(const bf16x8*)&As[(w << 5) + (mt << 4) + m16][q << 3];
#pragma unroll
    for (int nt = 0; nt < 8; nt++)
      bfv[nt] = *(const bf16x8*)&Bs[(nt << 4) + m16][q << 3];
#pragma unroll
    for (int mt = 0; mt < 2; mt++)
#pragma unroll
      for (int nt = 0; nt < 8; nt++)
        acc[mt][nt] = __builtin_amdgcn_mfma_f32_16x16x32_bf16(af[mt], bfv[nt], acc[mt][nt], 0, 0, 0);
    __syncthreads();
  }
#pragma unroll
  for (int mt = 0; mt < 2; mt++)
#pragma unroll
    for (int nt = 0; nt < 8; nt++)
#pragma unroll
      for (int i = 0; i < 4; i++) {
        const int grow = m0 + (w << 5) + (mt << 4) + (q << 2) + i;
        const int gcol = n0 + (nt << 4) + m16;
        float v = fmaxf(acc[mt][nt][i] + bias[gcol], 0.f);
        const int col = coloff + gcol;
        const int tt = grow >> 5, b = grow & 31;
        C[((size_t)tt * 64 + (col >> 4)) * 512 + b * 16 + (col & 15)] = f2bf(v);
      }
}

// Fused 2-layer x 2-direction GRU, software-pipelined periods.
// grid = 256 = 4 groups x 64 blocks: 0=L0f, 1=L0b, 2=L1f, 3=L1b. Block owns 16 dims.
// Per period p (0..256):
//   waves 2-3 (x-waves): compute Wih @ src[p] -> xbuf[p&1]   (one period AHEAD of use;
//       L0: src=x0, never waits; L1: waits srcf >= p+1, usually already satisfied)
//   waves 0-1 (h-waves): wait ownf >= p-1, load y[p-2], compute Whh @ h -> hgp
//   B1; all threads: gates for t=p-1 (consume hgp + xbuf[(p-1)&1]), h regs, hout
//   B2; wave 3 alone: 1KB sc1 chunk store, vmcnt drain, flag ownf[g]=p
// Sync primitives identical to round 4 (relaxed agent atomics for flags, sc1 data
// stores, plain cached data loads guarded by flags; kernel-launch L1/L2 invalidate).
__global__ __launch_bounds__(256, 1) void gru_fused(
    const float* __restrict__ Whh_f, const float* __restrict__ Whh_b,
    const float* __restrict__ Wih_f, const float* __restrict__ Wih_b,
    const float* __restrict__ bih_f, const float* __restrict__ bhh_f,
    const float* __restrict__ bih_b, const float* __restrict__ bhh_b,
    const short* __restrict__ x0,
    short* __restrict__ y0f, short* __restrict__ y0b,
    short* __restrict__ y1f, short* __restrict__ y1b,
    int* __restrict__ ctrl) {
  const int group = blockIdx.x >> 6;  // 0..3
  const int g = blockIdx.x & 63;
  const size_t WL = (size_t)3072 * 1024;

  const float* Wrec; const float* Win; const float* bih; const float* bhh;
  const short* src; short* y; int* ownf; const int* srcf;
  switch (group) {
    case 0:  Wrec = Whh_f;      Win = Wih_f;      bih = bih_f;        bhh = bhh_f;
             src = x0;  y = y0f; ownf = ctrl;       srcf = nullptr;    break;
    case 1:  Wrec = Whh_b;      Win = Wih_b;      bih = bih_b;        bhh = bhh_b;
             src = x0;  y = y0b; ownf = ctrl + 64;  srcf = nullptr;    break;
    case 2:  Wrec = Whh_f + WL; Win = Wih_f + WL; bih = bih_f + 3072; bhh = bhh_f + 3072;
             src = y0f; y = y1f; ownf = ctrl + 128; srcf = ctrl;       break;
    default: Wrec = Whh_b + WL; Win = Wih_b + WL; bih = bih_b + 3072; bhh = bhh_b + 3072;
             src = y0b; y = y1b; ownf = ctrl + 192; srcf = ctrl + 64;  break;
  }

  const int tid = threadIdx.x;
  const int w = tid >> 6, lane = tid & 63, m16 = lane & 15, q = lane >> 4;
  const int d0 = g << 4;

  // ---- preload weight slice as A-frags (fp32 -> bf16): 192 VGPRs ----
  const float* Wsrc = (w < 2) ? Wrec : Win;
  const int kb0 = (w & 1) << 9;
  bf16x8 a[3][16];
#pragma unroll
  for (int mt = 0; mt < 3; mt++) {
    const size_t row = (size_t)(mt << 10) + d0 + m16;
#pragma unroll
    for (int ks = 0; ks < 16; ks++) {
      const int k = kb0 + (ks << 5) + (q << 3);
      const f32x4* wp = (const f32x4*)(Wsrc + row * 1024 + k);
      f32x4 lo = wp[0], hi = wp[1];
      bf16x8 t;
      t[0] = f2bf(lo.x); t[1] = f2bf(lo.y); t[2] = f2bf(lo.z); t[3] = f2bf(lo.w);
      t[4] = f2bf(hi.x); t[5] = f2bf(hi.y); t[6] = f2bf(hi.z); t[7] = f2bf(hi.w);
      a[mt][ks] = t;
    }
  }

  const int dd = tid & 15, bq = tid >> 4;
  const int dg = d0 + dd;
  const float Cr = bih[dg] + bhh[dg];
  const float Cz = bih[1024 + dg] + bhh[1024 + dg];
  const float bni = bih[2048 + dg], bnh = bhh[2048 + dg];
  float h[2] = {0.f, 0.f};

  __shared__ float hgp[2 * 48 * 33];      // h-part partials (waves 0-1)
  __shared__ float xbuf[2][2 * 48 * 33];  // x-part partials, double-buffered
  __shared__ short hout[512];             // chunk image: [b][dl] = b*16+dl
  const f32x4 vzero = {0.f, 0.f, 0.f, 0.f};

  for (int p = 0; p <= 256; p++) {
    // ---- wave-local dependency polls (no block barrier before loads) ----
    if (w < 2) {
      if (p >= 2) {
        for (;;) {
          int v = __hip_atomic_load(ownf + lane, __ATOMIC_RELAXED, __HIP_MEMORY_SCOPE_AGENT);
          if (__all(v >= p - 1)) break;
          __builtin_amdgcn_s_sleep(1);
        }
      }
    } else if (srcf && p < 256) {
      for (;;) {
        int v = __hip_atomic_load(srcf + lane, __ATOMIC_RELAXED, __HIP_MEMORY_SCOPE_AGENT);
        if (__all(v >= p + 1)) break;
        __builtin_amdgcn_s_sleep(1);
      }
    }

    f32x4 acc[3][2];
#pragma unroll
    for (int mt = 0; mt < 3; mt++) { acc[mt][0] = vzero; acc[mt][1] = vzero; }

    const bool hact = (w < 2) && (p >= 2);
    const bool xact = (w >= 2) && (p < 256);
    if (hact || xact) {
      const short* buf = (w < 2) ? (y + (size_t)(p - 2) * 32768)
                                 : (src + (size_t)p * 32768);
      const int boff = (q & 1) << 3;
#pragma unroll
      for (int ks = 0; ks < 16; ks++) {
        const int c16 = ((w & 1) << 5) + (ks << 1) + (q >> 1);
        const short* cp = buf + (size_t)c16 * 512 + boff;
        bf16x8 b0 = *(const bf16x8*)(cp + m16 * 16);
        bf16x8 b1 = *(const bf16x8*)(cp + (m16 + 16) * 16);
#pragma unroll
        for (int mt = 0; mt < 3; mt++) {
          acc[mt][0] = __builtin_amdgcn_mfma_f32_16x16x32_bf16(a[mt][ks], b0, acc[mt][0], 0, 0, 0);
          acc[mt][1] = __builtin_amdgcn_mfma_f32_16x16x32_bf16(a[mt][ks], b1, acc[mt][1], 0, 0, 0);
        }
      }
    }
    {
      float* dst = (w < 2) ? (hgp + (size_t)w * 1584)
                           : (xbuf[p & 1] + (size_t)(w & 1) * 1584);
#pragma unroll
      for (int mt = 0; mt < 3; mt++)
#pragma unroll
        for (int nt = 0; nt < 2; nt++)
#pragma unroll
          for (int i = 0; i < 4; i++)
            dst[(mt * 16 + (q << 2) + i) * 33 + (nt << 4) + m16] = acc[mt][nt][i];
    }
    __syncthreads();

    // ---- gates for t = p-1 ----
    if (p >= 1) {
      const float* xb = xbuf[(p - 1) & 1];
#pragma unroll
      for (int k2 = 0; k2 < 2; k2++) {
        const int b = bq + (k2 << 4);
        const float rs = hgp[dd * 33 + b] + hgp[(48 + dd) * 33 + b] +
                         xb[dd * 33 + b] + xb[(48 + dd) * 33 + b] + Cr;
        const float zs = hgp[(16 + dd) * 33 + b] + hgp[(64 + dd) * 33 + b] +
                         xb[(16 + dd) * 33 + b] + xb[(64 + dd) * 33 + b] + Cz;
        const float hn = hgp[(32 + dd) * 33 + b] + hgp[(80 + dd) * 33 + b];
        const float xn = xb[(32 + dd) * 33 + b] + xb[(80 + dd) * 33 + b];
        const float rr = sigmf(rs);
        const float zz = sigmf(zs);
        const float nn = tanhf(xn + bni + rr * (hn + bnh));
        h[k2] = (1.f - zz) * nn + zz * h[k2];
        hout[b * 16 + dd] = f2bf(h[k2]);
      }
    }
    __syncthreads();

    // ---- wave 3 alone: publish chunk (t=p-1, g) + flag; others roll on ----
    if (p >= 1 && w == 3) {
      union { bf16x8 v; unsigned long long u[2]; } pk;
      pk.v = *(const bf16x8*)&hout[lane * 8];
      short* dst = y + (size_t)(p - 1) * 32768 + (size_t)g * 512 + lane * 8;
      __hip_atomic_store((unsigned long long*)dst, pk.u[0],
                         __ATOMIC_RELAXED, __HIP_MEMORY_SCOPE_AGENT);
      __hip_atomic_store((unsigned long long*)(dst + 4), pk.u[1],
                         __ATOMIC_RELAXED, __HIP_MEMORY_SCOPE_AGENT);
      asm volatile("s_waitcnt vmcnt(0)" ::: "memory");
      if (lane == 0)
        __hip_atomic_store(ownf + g, p, __ATOMIC_RELAXED, __HIP_MEMORY_SCOPE_AGENT);
    }
  }
}

// y1 f/b in chunk-16 layout: elem(r=t*32+b, c) at ((t*64 + (c>>4))*512 + b*16 + (c&15))
__global__ __launch_bounds__(256) void final_dot(
    const short* __restrict__ yF, const short* __restrict__ yB,
    const float* __restrict__ Wo, const float* __restrict__ bo,
    float* __restrict__ partials) {
  const int w = threadIdx.x >> 6, lane = threadIdx.x & 63;
  __shared__ float red[4];
  float acc = 0.f;
  const int r0 = (blockIdx.x << 7) + (w << 5);
  for (int rr = 0; rr < 32; rr++) {
    const int r = r0 + rr;
    const size_t rbase = (size_t)(r >> 5) * 32768 + (size_t)(r & 31) * 16;
    float s = 0.f;
    for (int c = lane; c < 1024; c += 64) {
      const size_t idx = rbase + (size_t)(c >> 4) * 512 + (c & 15);
      s += (bf2f(yF[idx]) + bf2f(yB[idx])) * Wo[c];
    }
#pragma unroll
    for (int off = 32; off > 0; off >>= 1) s += __shfl_down(s, off);
    if (lane == 0) acc += sigmf(s + bo[0]);
  }
  if (lane == 0) red[w] = acc;
  __syncthreads();
  if (threadIdx.x == 0) partials[blockIdx.x] = red[0] + red[1] + red[2] + red[3];
}

__global__ void final_reduce(const float* __restrict__ partials, float* __restrict__ out) {
  float s = partials[threadIdx.x];
#pragma unroll
  for (int off = 32; off > 0; off >>= 1) s += __shfl_down(s, off);
  if (threadIdx.x == 0) out[0] = s * (1.f / 8192.f);
}

extern "C" void kernel_launch(void* const* d_in, const int* in_sizes, int n_in,
                              void* d_out, int out_size, void* d_ws, size_t ws_size,
                              hipStream_t stream) {
  const float* in_x  = (const float*)d_in[0];   // [32,256,72]
  const float* in_c  = (const float*)d_in[1];   // [32,256,80]
  const float* Wc    = (const float*)d_in[2];   // [512,80]
  const float* bc    = (const float*)d_in[3];
  const float* Wi    = (const float*)d_in[4];   // [512,72]
  const float* bi    = (const float*)d_in[5];
  const float* Wih_f = (const float*)d_in[6];   // [2,3072,1024]
  const float* Whh_f = (const float*)d_in[7];
  const float* bih_f = (const float*)d_in[8];
  const float* bhh_f = (const float*)d_in[9];
  const float* Wih_b = (const float*)d_in[10];
  const float* Whh_b = (const float*)d_in[11];
  const float* bih_b = (const float*)d_in[12];
  const float* bhh_b = (const float*)d_in[13];
  const float* Wo    = (const float*)d_in[14];  // [1,1024]
  const float* bo    = (const float*)d_in[15];
  float* out = (float*)d_out;

  char* base = (char*)d_ws;
  const size_t S1 = (size_t)8192 * 1024 * 2;  // 16.78 MB per [T*B,1024] bf16 buffer
  short* x0  = (short*)(base);                // layer-0 input; reused as y1f
  short* y0f = (short*)(base + S1);
  short* y0b = (short*)(base + 2 * S1);
  short* y1b = (short*)(base + 3 * S1);
  float* partials = (float*)(base + 4 * S1);
  int* ctrl = (int*)(base + 4 * S1 + 4096);
  short* y1f = x0;  // safe: x0 chunk t last read at L0 period t; y1[t] written at L1
                    // period t+1 >= 2 periods later

  hipMemsetAsync(ctrl, 0, 4096, stream);

  dim3 blk(256);
  proj_gemm<<<dim3(64, 4), blk, 0, stream>>>(in_c, 80, Wc, 80, bc, x0, 0, 80);
  proj_gemm<<<dim3(64, 4), blk, 0, stream>>>(in_x, 72, Wi, 72, bi, x0, 512, 72);
  gru_fused<<<dim3(256), blk, 0, stream>>>(Whh_f, Whh_b, Wih_f, Wih_b,
                                           bih_f, bhh_f, bih_b, bhh_b,
                                           x0, y0f, y0b, y1f, y1b, ctrl);
  final_dot<<<dim3(64), blk, 0, stream>>>(y1f, y1b, Wo, bo, partials);
  final_reduce<<<dim3(1), dim3(64), 0, stream>>>(partials, out);
}

// Round 6
// 2410.365 us; speedup vs baseline: 1.1301x; 1.1301x over previous
//
#include <hip/hip_runtime.h>

typedef __attribute__((ext_vector_type(8))) short bf16x8;
typedef __attribute__((ext_vector_type(4))) float f32x4;

__device__ __forceinline__ short f2bf(float f) {
  union { float f; unsigned u; } v; v.f = f;
  unsigned r = (v.u + 0x7fffu + ((v.u >> 16) & 1u)) >> 16;
  return (short)r;
}
__device__ __forceinline__ float bf2f(short s) {
  union { unsigned u; float f; } v; v.u = ((unsigned)(unsigned short)s) << 16;
  return v.f;
}
__device__ __forceinline__ float sigmf(float x) { return 1.f / (1.f + __expf(-x)); }

// sc0 dword load: L1-bypass, served by the XCD-shared L2 (fresh for same-XCD writers)
__device__ __forceinline__ int ld_sc0(const int* p) {
  int v;
  asm volatile("global_load_dword %0, %1, off sc0\n\ts_waitcnt vmcnt(0)"
               : "=v"(v) : "v"(p) : "memory");
  return v;
}
#define ALOAD(p)     __hip_atomic_load((p), __ATOMIC_RELAXED, __HIP_MEMORY_SCOPE_AGENT)
#define ASTORE(p, v) __hip_atomic_store((p), (v), __ATOMIC_RELAXED, __HIP_MEMORY_SCOPE_AGENT)

__device__ __forceinline__ void stage_row_f32(const float* __restrict__ src, short* dst,
                                              int kb, int k0, int K) {
  if (kb + k0 + 15 < K) {
    const f32x4* p4 = (const f32x4*)src;
#pragma unroll
    for (int g = 0; g < 4; g++) {
      f32x4 v = p4[g];
      dst[g * 4 + 0] = f2bf(v.x); dst[g * 4 + 1] = f2bf(v.y);
      dst[g * 4 + 2] = f2bf(v.z); dst[g * 4 + 3] = f2bf(v.w);
    }
  } else {
#pragma unroll
    for (int j = 0; j < 16; j++) {
      float v = (kb + k0 + j < K) ? src[j] : 0.f;
      dst[j] = f2bf(v);
    }
  }
}

// Input projection: relu(A @ W^T + b). A fp32 [B,T,K] (logical row r=t*32+b at phys
// b*256+t). C bf16 in chunk-32 layout: elem(r=t*32+b, col) at
//   ((t*32 + (col>>5))*32 + b)*32 + (col&31).
__global__ __launch_bounds__(256) void proj_gemm(
    const float* __restrict__ A, int lda,
    const float* __restrict__ W, int ldw,
    const float* __restrict__ bias,
    short* __restrict__ C, int coloff, int K) {
  __shared__ short As[128][40];
  __shared__ short Bs[128][40];
  const int tid = threadIdx.x;
  const int m0 = blockIdx.x << 7, n0 = blockIdx.y << 7;
  const int w = tid >> 6, lane = tid & 63, m16 = lane & 15, q = lane >> 4;
  const f32x4 vzero = {0.f, 0.f, 0.f, 0.f};
  f32x4 acc[2][8];
#pragma unroll
  for (int mt = 0; mt < 2; mt++)
#pragma unroll
    for (int nt = 0; nt < 8; nt++) acc[mt][nt] = vzero;

  const int nk = (K + 31) >> 5;
  const int r = tid >> 1, k0 = (tid & 1) << 4;
  for (int kc = 0; kc < nk; kc++) {
    const int kb = kc << 5;
    {
      const int gr = m0 + r;
      const size_t arow = (size_t)(gr & 31) * 256 + (size_t)(gr >> 5);
      stage_row_f32(A + arow * (size_t)lda + kb + k0, &As[r][k0], kb, k0, K);
    }
    {
      const float* bp = W + (size_t)(n0 + r) * ldw + kb + k0;
      stage_row_f32(bp, &Bs[r][k0], kb, k0, K);
    }
    __syncthreads();
    bf16x8 af[2], bfv[8];
#pragma unroll
    for (int mt = 0; mt < 2; mt++)
      af[mt] = *(const bf16x8*)&As[(w << 5) + (mt << 4) + m16][q << 3];
#pragma unroll
    for (int nt = 0; nt < 8; nt++)
      bfv[nt] = *(const bf16x8*)&Bs[(nt << 4) + m16][q << 3];
#pragma unroll
    for (int mt = 0; mt < 2; mt++)
#pragma unroll
      for (int nt = 0; nt < 8; nt++)
        acc[mt][nt] = __builtin_amdgcn_mfma_f32_16x16x32_bf16(af[mt], bfv[nt], acc[mt][nt], 0, 0, 0);
    __syncthreads();
  }
#pragma unroll
  for (int mt = 0; mt < 2; mt++)
#pragma unroll
    for (int nt = 0; nt < 8; nt++)
#pragma unroll
      for (int i = 0; i < 4; i++) {
        const int grow = m0 + (w << 5) + (mt << 4) + (q << 2) + i;
        const int gcol = n0 + (nt << 4) + m16;
        float v = fmaxf(acc[mt][nt][i] + bias[gcol], 0.f);
        const int col = coloff + gcol;
        const int tt = grow >> 5, b = grow & 31;
        C[(((size_t)tt * 32 + (col >> 5)) * 32 + b) * 32 + (col & 31)] = f2bf(v);
      }
}

// ============================================================================
// Persistent fused kernel: 8 groups x 32 blocks (group = blockIdx&7 -> one XCD
// per group under SPX round-robin; correctness does NOT depend on this).
// Groups 0-3: h-chains (L0f,L0b,L1f,L1b), 32 dims/block.
// Groups 4-7: farms computing Wih @ src[t] chunks for h-group (gid-4).
// Sync: local flags (plain store -> sc0 poll, XCD-L2) with unconditional MALL
// mirror (wave-3 sc1 chunk copy + drained sc1 flag). Bounded local polls latch
// to mirror mode on failure -> deadlock impossible under ANY block placement.
// Cross-group hops (L0->farm, farm->h) always via MALL flags (proven prims);
// they are pipelined streams (constant offset, not rate).
// y layout: y[t][rank][b][dl] (2KB chunks). xg rings: [slot32][rank][gate][b][dd].
// ============================================================================
__global__ __launch_bounds__(256, 1) void gru_giant(
    const float* __restrict__ Whh_f, const float* __restrict__ Whh_b,
    const float* __restrict__ Wih_f, const float* __restrict__ Wih_b,
    const float* __restrict__ bih_f, const float* __restrict__ bhh_f,
    const float* __restrict__ bih_b, const float* __restrict__ bhh_b,
    const short* __restrict__ x0c, short* __restrict__ ybase,
    short* __restrict__ ringbase, int* __restrict__ ctrl) {
  const int gid = blockIdx.x & 7;
  const int r = blockIdx.x >> 3;
  const int tid = threadIdx.x;
  const int w = tid >> 6, lane = tid & 63, m16 = lane & 15, q = lane >> 4;

  __shared__ float hgp[4 * 96 * 33];  // [wave][row=gate*32+dd][col=b(+pad)]
  __shared__ short hout[32 * 40];
  __shared__ int smode[2];            // [0]=mirror latch, [1]=fr/bp cache

  const int hgrp = (gid < 4) ? gid : (gid - 4);
  const int layer = hgrp >> 1, chain = hgrp & 1;
  const size_t WL = (size_t)3072 * 1024;
  const float* Wsl = ((gid < 4) ? (chain ? Whh_b : Whh_f)
                                : (chain ? Wih_b : Wih_f)) + layer * WL;

  // ---- preload weight slice as A-frags (96 rows x 1024, fp32->bf16) ----
  const int d0 = r << 5;
  const int kw = w << 8;
  bf16x8 a[6][8];
#pragma unroll
  for (int mt = 0; mt < 6; mt++) {
    const int row = (mt >> 1) * 1024 + d0 + ((mt & 1) << 4) + m16;
#pragma unroll
    for (int ks = 0; ks < 8; ks++) {
      const int kk = kw + ks * 32 + (q << 3);
      const f32x4* wp = (const f32x4*)(Wsl + (size_t)row * 1024 + kk);
      f32x4 lo = wp[0], hi = wp[1];
      bf16x8 t;
      t[0] = f2bf(lo.x); t[1] = f2bf(lo.y); t[2] = f2bf(lo.z); t[3] = f2bf(lo.w);
      t[4] = f2bf(hi.x); t[5] = f2bf(hi.y); t[6] = f2bf(hi.z); t[7] = f2bf(hi.w);
      a[mt][ks] = t;
    }
  }

  // ---- rendezvous (removes preload skew so local-poll bounds are honest) ----
  if (tid == 0) {
    (void)__hip_atomic_fetch_add(ctrl + 400, 1, __ATOMIC_RELAXED, __HIP_MEMORY_SCOPE_AGENT);
    smode[0] = 0; smode[1] = 0;
  }
  if (w == 0) {
    while (ALOAD(ctrl + 400) < 256) __builtin_amdgcn_s_sleep(4);
  }
  __syncthreads();

  int* lflag = ctrl + hgrp * 32;
  int* mir   = ctrl + 128 + hgrp * 32;
  int* fr    = ctrl + 256 + hgrp * 32;
  short* y    = ybase + (size_t)hgrp * 8388608;
  short* ring = ringbase + (size_t)hgrp * 3145728;
  const f32x4 vz = {0.f, 0.f, 0.f, 0.f};

  if (gid < 4) {
    // ================= h-chain block =================
    const float* bih = (chain ? bih_b : bih_f) + layer * 3072;
    const float* bhh = (chain ? bhh_b : bhh_f) + layer * 3072;
    const int dd = tid & 31, bq = tid >> 5;
    const int dg = d0 + dd;
    const float Cr = bih[dg] + bhh[dg];
    const float Cz = bih[1024 + dg] + bhh[1024 + dg];
    const float bni = bih[2048 + dg], bnh = bhh[2048 + dg];
    float h[4] = {0.f, 0.f, 0.f, 0.f};

    for (int t = 0; t < 256; t++) {
      // ---- own-group flag wait (need y[t-1] from all 32 ranks) ----
      if (t > 0) {
        if (smode[0] == 0) {
          bool ok = false;
          for (int it = 0; it < 256; it++) {
            int v = ld_sc0(lflag + (lane & 31));
            if (__all(v >= t)) { ok = true; break; }
            if (it > 8) __builtin_amdgcn_s_sleep(1);
          }
          if (!ok) smode[0] = 1;  // latch to MALL mirror (benign LDS race)
        }
        if (smode[0]) {
          for (;;) {
            int v = ALOAD(mir + (lane & 31));
            if (__all(v >= t)) break;
            __builtin_amdgcn_s_sleep(1);
          }
        }
      }
      // ---- farm flag (cached; farm runs ahead so this rarely polls) ----
      if (smode[1] < t + 1) {
        for (;;) {
          int v = ALOAD(fr + r);
          if (v >= t + 1) { smode[1] = v; break; }
          __builtin_amdgcn_s_sleep(1);
        }
      }
      // ---- xg pre-loads (sc1: ring slots are address-reused -> must bypass caches)
      unsigned xgv[12];
      {
        const short* cb = ring + ((size_t)(t & 31) * 32 + r) * 3072;
#pragma unroll
        for (int k2 = 0; k2 < 4; k2++) {
          const int b = bq + (k2 << 3);
#pragma unroll
          for (int gate = 0; gate < 3; gate++)
            xgv[k2 * 3 + gate] =
                ALOAD((const unsigned*)(cb + (gate * 32 + b) * 32 + (dd & ~1)));
        }
      }
      // ---- h-part MFMA on y[t-1] (plain cached loads; first-touch per line) ----
      f32x4 acc[6][2];
#pragma unroll
      for (int mt = 0; mt < 6; mt++) { acc[mt][0] = vz; acc[mt][1] = vz; }
      if (t > 0) {
        const short* yc = y + (size_t)(t - 1) * 32768;
        bf16x8 bfr[2][8];
#pragma unroll
        for (int nt = 0; nt < 2; nt++) {
          const int n = (nt << 4) + m16;
#pragma unroll
          for (int ks = 0; ks < 8; ks++) {
            const int gk = (w << 3) + ks;
            bfr[nt][ks] = *(const bf16x8*)(yc + (size_t)gk * 1024 + n * 32 + (q << 3));
          }
        }
#pragma unroll
        for (int ks = 0; ks < 8; ks++)
#pragma unroll
          for (int mt = 0; mt < 6; mt++)
#pragma unroll
            for (int nt = 0; nt < 2; nt++)
              acc[mt][nt] = __builtin_amdgcn_mfma_f32_16x16x32_bf16(a[mt][ks], bfr[nt][ks], acc[mt][nt], 0, 0, 0);
      }
#pragma unroll
      for (int mt = 0; mt < 6; mt++)
#pragma unroll
        for (int nt = 0; nt < 2; nt++)
#pragma unroll
          for (int i = 0; i < 4; i++)
            hgp[((size_t)w * 96 + mt * 16 + (q << 2) + i) * 33 + (nt << 4) + m16] = acc[mt][nt][i];
      __syncthreads();

      // ---- gates ----
#pragma unroll
      for (int k2 = 0; k2 < 4; k2++) {
        const int b = bq + (k2 << 3);
        float hr = 0.f, hz = 0.f, hn = 0.f;
#pragma unroll
        for (int ww = 0; ww < 4; ww++) {
          hr += hgp[((size_t)ww * 96 + dd) * 33 + b];
          hz += hgp[((size_t)ww * 96 + 32 + dd) * 33 + b];
          hn += hgp[((size_t)ww * 96 + 64 + dd) * 33 + b];
        }
        const unsigned ur = xgv[k2 * 3 + 0], uz = xgv[k2 * 3 + 1], un = xgv[k2 * 3 + 2];
        const int hi = dd & 1;
        const float xr = bf2f((short)(hi ? (ur >> 16) : (ur & 0xFFFF)));
        const float xz = bf2f((short)(hi ? (uz >> 16) : (uz & 0xFFFF)));
        const float xn = bf2f((short)(hi ? (un >> 16) : (un & 0xFFFF)));
        const float rr = sigmf(xr + Cr + hr);
        const float zz = sigmf(xz + Cz + hz);
        const float nn = tanhf(xn + bni + rr * (hn + bnh));
        h[k2] = (1.f - zz) * nn + zz * h[k2];
        hout[b * 40 + dd] = f2bf(h[k2]);
      }
      __syncthreads();

      // ---- publish chunk (t, r): plain (local L2) ----
      {
        const int b = tid >> 3, c = (tid & 7) << 2;
        *(unsigned long long*)(y + ((size_t)t * 32 + r) * 1024 + b * 32 + c) =
            *(const unsigned long long*)&hout[b * 40 + c];
      }
      __syncthreads();  // implicit per-wave vmcnt drain -> chunk is in local L2
      if (tid == 0) *(volatile int*)(lflag + r) = t + 1;  // local flag
      // ---- unconditional MALL mirror (wave 3): sc1 copy + drained sc1 flag ----
      if (w == 3) {
        const int b2 = lane >> 1, dl0 = (lane & 1) << 4;
        const unsigned long long* sp = (const unsigned long long*)&hout[b2 * 40 + dl0];
        unsigned long long* dp =
            (unsigned long long*)(y + ((size_t)t * 32 + r) * 1024 + b2 * 32 + dl0);
#pragma unroll
        for (int j = 0; j < 4; j++) ASTORE(dp + j, sp[j]);
        asm volatile("s_waitcnt vmcnt(0)" ::: "memory");
        if (lane == 0) ASTORE(mir + r, t + 1);
      }
    }
  } else {
    // ================= farm block: xg[t] = Wih_slice @ src[t], 2 steps/iter ====
    const short* src = (layer == 0) ? x0c : (ybase + (size_t)chain * 8388608);
    const int* srcmir = (layer == 0) ? nullptr : (ctrl + 128 + chain * 32);
    for (int t = 0; t < 256; t += 2) {
      if (srcmir) {  // need src[t], src[t+1]
        for (;;) {
          int v = ALOAD(srcmir + (lane & 31));
          if (__all(v >= t + 2)) break;
          __builtin_amdgcn_s_sleep(1);
        }
      }
      if (t >= 24 && smode[1] < t - 22) {  // ring backpressure vs consumer rank r
        for (;;) {
          int v = ALOAD(mir + r);
          if (v >= t - 22) { smode[1] = v; break; }
          __builtin_amdgcn_s_sleep(1);
        }
      }
      f32x4 acc0[6][2], acc1[6][2];
#pragma unroll
      for (int mt = 0; mt < 6; mt++) {
        acc0[mt][0] = vz; acc0[mt][1] = vz; acc1[mt][0] = vz; acc1[mt][1] = vz;
      }
#pragma unroll
      for (int half = 0; half < 2; half++) {
        const short* sc = src + (size_t)(t + half) * 32768;
        bf16x8 bfr[2][8];
#pragma unroll
        for (int nt = 0; nt < 2; nt++) {
          const int n = (nt << 4) + m16;
#pragma unroll
          for (int ks = 0; ks < 8; ks++) {
            const int gk = (w << 3) + ks;
            bfr[nt][ks] = *(const bf16x8*)(sc + (size_t)gk * 1024 + n * 32 + (q << 3));
          }
        }
#pragma unroll
        for (int ks = 0; ks < 8; ks++)
#pragma unroll
          for (int mt = 0; mt < 6; mt++)
#pragma unroll
            for (int nt = 0; nt < 2; nt++) {
              if (half == 0)
                acc0[mt][nt] = __builtin_amdgcn_mfma_f32_16x16x32_bf16(a[mt][ks], bfr[nt][ks], acc0[mt][nt], 0, 0, 0);
              else
                acc1[mt][nt] = __builtin_amdgcn_mfma_f32_16x16x32_bf16(a[mt][ks], bfr[nt][ks], acc1[mt][nt], 0, 0, 0);
            }
      }
#pragma unroll
      for (int half = 0; half < 2; half++) {
#pragma unroll
        for (int mt = 0; mt < 6; mt++)
#pragma unroll
          for (int nt = 0; nt < 2; nt++)
#pragma unroll
            for (int i = 0; i < 4; i++)
              hgp[((size_t)w * 96 + mt * 16 + (q << 2) + i) * 33 + (nt << 4) + m16] =
                  (half == 0) ? acc0[mt][nt][i] : acc1[mt][nt][i];
        __syncthreads();
        if (tid < 192) {  // 4-wave reduce + pack + sc1 store of 6KB chunk
          const int l0 = tid << 4;
          const int gate = l0 >> 10, b = (l0 >> 5) & 31, dd0 = l0 & 31;
          short tmp[16];
#pragma unroll
          for (int j = 0; j < 16; j++) {
            float s = 0.f;
#pragma unroll
            for (int ww = 0; ww < 4; ww++)
              s += hgp[((size_t)ww * 96 + gate * 32 + dd0 + j) * 33 + b];
            tmp[j] = f2bf(s);
          }
          unsigned long long* dp = (unsigned long long*)(
              ring + ((size_t)((t + half) & 31) * 32 + r) * 3072 + l0);
          const unsigned long long* sp = (const unsigned long long*)tmp;
#pragma unroll
          for (int j = 0; j < 4; j++) ASTORE(dp + j, sp[j]);
        }
        __syncthreads();  // implicit drain; also guards hgp overwrite
      }
      if (tid == 0) ASTORE(fr + r, t + 2);
    }
  }
}

// y1 chunk-32 layout: elem(row=t*32+b, c) at ((t*32 + (c>>5))*32 + b)*32 + (c&31)
__global__ __launch_bounds__(256) void final_dot(
    const short* __restrict__ yF, const short* __restrict__ yB,
    const float* __restrict__ Wo, const float* __restrict__ bo,
    float* __restrict__ partials) {
  const int w = threadIdx.x >> 6, lane = threadIdx.x & 63;
  __shared__ float red[4];
  float acc = 0.f;
  const int r0 = (blockIdx.x << 7) + (w << 5);
  for (int rr = 0; rr < 32; rr++) {
    const int r = r0 + rr;
    const size_t rbase = (size_t)(r >> 5) * 32768 + (size_t)(r & 31) * 32;
    float s = 0.f;
    for (int c = lane; c < 1024; c += 64) {
      const size_t idx = rbase + (size_t)(c >> 5) * 1024 + (c & 31);
      s += (bf2f(yF[idx]) + bf2f(yB[idx])) * Wo[c];
    }
#pragma unroll
    for (int off = 32; off > 0; off >>= 1) s += __shfl_down(s, off);
    if (lane == 0) acc += sigmf(s + bo[0]);
  }
  if (lane == 0) red[w] = acc;
  __syncthreads();
  if (threadIdx.x == 0) partials[blockIdx.x] = red[0] + red[1] + red[2] + red[3];
}

__global__ void final_reduce(const float* __restrict__ partials, float* __restrict__ out) {
  float s = partials[threadIdx.x];
#pragma unroll
  for (int off = 32; off > 0; off >>= 1) s += __shfl_down(s, off);
  if (threadIdx.x == 0) out[0] = s * (1.f / 8192.f);
}

extern "C" void kernel_launch(void* const* d_in, const int* in_sizes, int n_in,
                              void* d_out, int out_size, void* d_ws, size_t ws_size,
                              hipStream_t stream) {
  const float* in_x  = (const float*)d_in[0];   // [32,256,72]
  const float* in_c  = (const float*)d_in[1];   // [32,256,80]
  const float* Wc    = (const float*)d_in[2];   // [512,80]
  const float* bc    = (const float*)d_in[3];
  const float* Wi    = (const float*)d_in[4];   // [512,72]
  const float* bi    = (const float*)d_in[5];
  const float* Wih_f = (const float*)d_in[6];   // [2,3072,1024]
  const float* Whh_f = (const float*)d_in[7];
  const float* bih_f = (const float*)d_in[8];
  const float* bhh_f = (const float*)d_in[9];
  const float* Wih_b = (const float*)d_in[10];
  const float* Whh_b = (const float*)d_in[11];
  const float* bih_b = (const float*)d_in[12];
  const float* bhh_b = (const float*)d_in[13];
  const float* Wo    = (const float*)d_in[14];  // [1,1024]
  const float* bo    = (const float*)d_in[15];
  float* out = (float*)d_out;

  char* base = (char*)d_ws;
  const size_t SX = (size_t)8192 * 1024 * 2;        // 16.78 MB x0 chunk buffer
  const size_t SY = (size_t)8192 * 1024 * 2;        // per y buffer
  const size_t SR = (size_t)32 * 32 * 3072 * 2;     // 6.29 MB per xg ring
  short* x0c  = (short*)(base);
  short* ybase = (short*)(base + SX);               // 4 buffers (L0f,L0b,L1f,L1b)
  short* ringbase = (short*)(base + SX + 4 * SY);   // 4 rings
  float* partials = (float*)(base + SX + 4 * SY + 4 * SR);
  int* ctrl = (int*)(base + SX + 4 * SY + 4 * SR + 4096);
  // total ws use ~109 MB

  hipMemsetAsync(ctrl, 0, 2048, stream);

  dim3 blk(256);
  proj_gemm<<<dim3(64, 4), blk, 0, stream>>>(in_c, 80, Wc, 80, bc, x0c, 0, 80);
  proj_gemm<<<dim3(64, 4), blk, 0, stream>>>(in_x, 72, Wi, 72, bi, x0c, 512, 72);
  gru_giant<<<dim3(256), blk, 0, stream>>>(Whh_f, Whh_b, Wih_f, Wih_b,
                                           bih_f, bhh_f, bih_b, bhh_b,
                                           x0c, ybase, ringbase, ctrl);
  short* y1f = ybase + (size_t)2 * 8388608;
  short* y1b = ybase + (size_t)3 * 8388608;
  final_dot<<<dim3(64), blk, 0, stream>>>(y1f, y1b, Wo, bo, partials);
  final_reduce<<<dim3(1), dim3(64), 0, stream>>>(partials, out);
}